// Round 10
// baseline (64.213 us; speedup 1.0000x reference)
//
#include <hip/hip_runtime.h>
#include <hip/hip_bf16.h>

#define T_IN   16
#define T_OUT  25
#define BHERO  4096
#define K_NBR  32
#define N_NBR  (BHERO * K_NBR)
#define ENC    64
#define DEC    128
#define DYN    32
#define EMB    32

#define EROW   104        // encoder slab row: [emb 32 | h 64] + pad (208 B)
#define DROW   136        // decoder slab row: 128 bf16 + pad (272 B)
#define RROW   40         // rela row: 32 feat + 8 pad (80 B)
#define SLABE  (16 * EROW * 2)   // 3328 B per encoder slab
#define SLABD  (16 * DROW * 2)   // 4352 B per decoder slab

// ---- LDS layout (byte offsets into one raw pool; phases overlay) ----
#define OFF_RELA   56576
#define OFF_PMAX   97536
#define OFF_ENC    113152
#define OFF_WOP    117504
#define OFF_WIP    118528
#define OFF_BIP    118784
#define OFF_BOP    118912
#define LDS_TOTAL  118928

#define L2E 1.44269504f   // log2(e); gate pre-scales fold the exp-arg mul into W/b

typedef __attribute__((ext_vector_type(8))) short bf16x8;   // 8 bf16 in 4 VGPRs
typedef __attribute__((ext_vector_type(4))) float f32x4;    // MFMA 16x16 C/D frag

__device__ __forceinline__ float lrelu(float x) { return x >= 0.f ? x : 0.1f * x; }
__device__ __forceinline__ float rcpf(float x)  { return __builtin_amdgcn_rcpf(x); }
__device__ __forceinline__ float ex2(float x)   { return __builtin_amdgcn_exp2f(x); }
// Activations on PRESCALED arguments (weights/bias already x L2E, g-gate x 2*L2E):
__device__ __forceinline__ float sigm2(float x) { return rcpf(1.f + ex2(-x)); }
__device__ __forceinline__ float tanh2(float x) { return fmaf(2.f, rcpf(1.f + ex2(-x)), -1.f); }
__device__ __forceinline__ float tanhc(float c) {
    return fmaf(2.f, rcpf(1.f + ex2(-2.f * L2E * c)), -1.f);
}
__device__ __forceinline__ unsigned pk2(float lo, float hi) {
    __hip_bfloat162 p = __float22bfloat162_rn(make_float2(lo, hi));
    unsigned u; __builtin_memcpy(&u, &p, 4); return u;
}
__device__ __forceinline__ bf16x8 mk_frag(float4 f0, float4 f1) {
    uint4 v = { pk2(f0.x, f0.y), pk2(f0.z, f0.w), pk2(f1.x, f1.y), pk2(f1.z, f1.w) };
    bf16x8 r; __builtin_memcpy(&r, &v, 16); return r;
}
__device__ __forceinline__ bf16x8 mk_frag_s(float4 f0, float4 f1, float s) {
    uint4 v = { pk2(f0.x*s, f0.y*s), pk2(f0.z*s, f0.w*s), pk2(f1.x*s, f1.y*s), pk2(f1.z*s, f1.w*s) };
    bf16x8 r; __builtin_memcpy(&r, &v, 16); return r;
}
__device__ __forceinline__ float bf2f(short s) {
    return __uint_as_float(((unsigned)(unsigned short)s) << 16);
}
// Light barrier: LDS-visibility only (lgkmcnt). Does NOT drain vmcnt — in-flight
// global loads span the barrier (their consumer is the same wave; per-wave vmcnt
// ordering guards correctness). All cross-wave dataflow in this kernel is LDS.
__device__ __forceinline__ void bar_lgkm() {
    asm volatile("s_waitcnt lgkmcnt(0)\n\ts_barrier" ::: "memory");
}

// ================= fused highwayNet forward: 256 WGs x 512 threads, 16 heroes/WG =================
__global__ __launch_bounds__(512, 2) void highway_fused(
    const float* __restrict__ hist,  const float* __restrict__ nbrs,
    const float* __restrict__ Wip,   const float* __restrict__ bip,
    const float* __restrict__ WihE,  const float* __restrict__ WhhE,
    const float* __restrict__ bihE,  const float* __restrict__ bhhE,
    const float* __restrict__ Wdyn,  const float* __restrict__ bdyn,
    const float* __restrict__ Wnbr,  const float* __restrict__ bnbr,
    const float* __restrict__ WihD,  const float* __restrict__ WhhD,
    const float* __restrict__ bihD,  const float* __restrict__ bhhD,
    const float* __restrict__ Wop,   const float* __restrict__ bop,
    const int*   __restrict__ seg,
    float* __restrict__ fut)                        // [T_OUT][BHERO][2]
{
    __shared__ __align__(16) char lds_raw[LDS_TOTAL];
    auto slab   = (short (*)[16][EROW])  lds_raw;                   // [17][16][EROW]
    auto rela2  = (short (*)[32][RROW]) (lds_raw + OFF_RELA);       // [2][32][RROW] rolling pairs
    auto pmax   = (float (*)[ENC])      (lds_raw + OFF_PMAX);       // [32][64]
    auto hist_s = (short (*)[16][DROW])  lds_raw;                   // [26][16][DROW]
    auto enc_s  = (float (*)[68])       (lds_raw + OFF_ENC);        // [16][68]
    auto wop_s  = (float (*)[DEC])      (lds_raw + OFF_WOP);        // [2][128]
    auto wip_s  = (float (*)[2])        (lds_raw + OFF_WIP);        // [32][2]
    auto bip_s  = (float*)              (lds_raw + OFF_BIP);        // [32]
    auto bop_s  = (float*)              (lds_raw + OFF_BOP);        // [2]

    const int b0  = blockIdx.x * 16;
    const int n0  = blockIdx.x * 512;               // first neighbor row of this WG
    const int tid = threadIdx.x;
    const int w = tid >> 6, l = tid & 63, r = l & 15, lg = l >> 4;

    // ---------------- P0: consts, zero slab0-h, frag prologues ----------------
    if (tid < EMB) {
        wip_s[tid][0] = Wip[2 * tid];
        wip_s[tid][1] = Wip[2 * tid + 1];
        bip_s[tid]    = bip[tid];
    }
    if (tid < 2 * DEC) wop_s[tid >> 7][tid & 127] = Wop[tid];
    if (tid < 2)       bop_s[tid] = bop[tid];
    for (int i = tid; i < 16 * ENC; i += 512) slab[0][i >> 6][32 + (i & 63)] = 0;

    // encoder B-frags (waves 0-3, prescaled) / nbr B-frags (waves 4-7, unscaled)
    bf16x8 BfE[4][3];
    float  biasE[4];
    bf16x8 BfN[2];
    float  biasn[2] = {0.f, 0.f};
    if (tid < 256) {
        #pragma unroll
        for (int j = 0; j < 4; ++j) {
            const float sj  = (j == 2) ? (2.f * L2E) : L2E;
            const int   col = j * ENC + w * 16 + r;
            biasE[j] = (bihE[col] + bhhE[col]) * sj;
            #pragma unroll
            for (int c = 0; c < 3; ++c) {
                const float* src = (c == 0) ? (WihE + (size_t)col * EMB + 8 * lg)
                                            : (WhhE + (size_t)col * ENC + (c - 1) * 32 + 8 * lg);
                BfE[j][c] = mk_frag_s(*(const float4*)src, *(const float4*)(src + 4), sj);
            }
        }
    } else {
        const int i = w - 4;
        const int ct0 = (i & 1) * 2;
        #pragma unroll
        for (int cc2 = 0; cc2 < 2; ++cc2) {
            const int col = (ct0 + cc2) * 16 + r;
            biasn[cc2] = bnbr[col];
            const float* src = Wnbr + (size_t)col * (2 * T_IN) + 8 * lg;
            BfN[cc2] = mk_frag(*(const float4*)src, *(const float4*)(src + 4));
        }
    }
    bar_lgkm();                                     // consts + slab0-h ready

    // ---------------- P1: emb prefill (waves 0-3) | rela pair 0 + pipeline prime (waves 4-7) ----------------
    // pipeline regs for waves 4-7 (statically named, rule-20 safe)
    float2 c_h0, c_v0, c_h1, c_v1;                  // pair t+1 data
    int    sg_c = 0;                                // seg value for pair t+2
    if (tid < 256) {
        const int t = tid >> 4, m = tid & 15;
        float2 hv = *(const float2*)&hist[((size_t)t * BHERO + b0 + m) * 2];
        #pragma unroll
        for (int jb = 0; jb < 4; ++jb) {
            float e[8];
            #pragma unroll
            for (int q = 0; q < 8; ++q) {
                int j = jb * 8 + q;
                e[q] = lrelu(hv.x * wip_s[j][0] + hv.y * wip_s[j][1] + bip_s[j]);
            }
            uint4 v = { pk2(e[0],e[1]), pk2(e[2],e[3]), pk2(e[4],e[5]), pk2(e[6],e[7]) };
            __builtin_memcpy(&slab[t][m][jb * 8], &v, 16);
        }
    } else {
        const int x    = tid - 256;
        const int nloc = x & 31;                    // local row in pair
        const int ts   = x >> 5;                    // 0..7 (also ts+8)
        // pair 0: load + write now
        {
            const int hb = seg[n0 + nloc];
            float2 h0 = *(const float2*)&hist[((size_t)ts * BHERO + hb) * 2];
            float2 v0 = *(const float2*)&nbrs[((size_t)ts * N_NBR + n0 + nloc) * 2];
            float2 h1 = *(const float2*)&hist[((size_t)(ts + 8) * BHERO + hb) * 2];
            float2 v1 = *(const float2*)&nbrs[((size_t)(ts + 8) * N_NBR + n0 + nloc) * 2];
            unsigned* dst = (unsigned*)&rela2[0][nloc][0];
            dst[ts]     = pk2(h0.x - v0.x, h0.y - v0.y);
            dst[ts + 8] = pk2(h1.x - v1.x, h1.y - v1.y);
        }
        // pair 1: issue loads into cur regs (consumed at interval 0)
        {
            const int n  = 32 + nloc;
            const int hb = seg[n0 + n];
            c_h0 = *(const float2*)&hist[((size_t)ts * BHERO + hb) * 2];
            c_v0 = *(const float2*)&nbrs[((size_t)ts * N_NBR + n0 + n) * 2];
            c_h1 = *(const float2*)&hist[((size_t)(ts + 8) * BHERO + hb) * 2];
            c_v1 = *(const float2*)&nbrs[((size_t)(ts + 8) * N_NBR + n0 + n) * 2];
        }
        sg_c = seg[n0 + 64 + nloc];                 // seg for pair 2
    }
    f32x4 cstE = {0.f, 0.f, 0.f, 0.f};              // cell state: hero 4*lg+q, unit w*16+r
    bar_lgkm();                                     // emb + rela pair 0 ready

    // ---------------- P2: encoder LSTM (waves 0-3) || pipelined nbr stage+GEMM (waves 4-7) ----------------
    {
        const char* rbase = lds_raw + (size_t)r * (EROW * 2);
        char*       wbase = lds_raw + SLABE + (size_t)(4 * lg) * (EROW * 2) + (size_t)(32 + w * 16 + r) * 2;
        const int   x    = tid - 256;               // valid for waves 4-7
        const int   nloc = x & 31;
        const int   ts   = x >> 5;
        #pragma unroll 1
        for (int t = 0; t < T_IN; ++t) {
            if (tid < 256) {
                const short* rp = (const short*)rbase;
                bf16x8 a0 = *(const bf16x8*)(rp + (0 + lg) * 8);
                bf16x8 a1 = *(const bf16x8*)(rp + (4 + lg) * 8);
                bf16x8 a2 = *(const bf16x8*)(rp + (8 + lg) * 8);
                f32x4 acc[4];
                #pragma unroll
                for (int j = 0; j < 4; ++j) {
                    f32x4 aA = (f32x4){biasE[j], biasE[j], biasE[j], biasE[j]};
                    f32x4 aB = (f32x4){0.f, 0.f, 0.f, 0.f};
                    aA = __builtin_amdgcn_mfma_f32_16x16x32_bf16(a0, BfE[j][0], aA, 0, 0, 0);
                    aB = __builtin_amdgcn_mfma_f32_16x16x32_bf16(a1, BfE[j][1], aB, 0, 0, 0);
                    aA = __builtin_amdgcn_mfma_f32_16x16x32_bf16(a2, BfE[j][2], aA, 0, 0, 0);
                    acc[j] = aA + aB;
                }
                float hq[4];
                #pragma unroll
                for (int q = 0; q < 4; ++q) {
                    float ii = sigm2(acc[0][q]);
                    float ff = sigm2(acc[1][q]);
                    float gg = tanh2(acc[2][q]);
                    float oo = sigm2(acc[3][q]);
                    float cc = fmaf(ff, cstE[q], ii * gg);
                    cstE[q] = cc;
                    hq[q] = oo * tanhc(cc);
                }
                unsigned u01 = pk2(hq[0], hq[1]), u23 = pk2(hq[2], hq[3]);
                short* wp = (short*)wbase;
                wp[0 * EROW] = (short)u01; wp[1 * EROW] = (short)(u01 >> 16);
                wp[2 * EROW] = (short)u23; wp[3 * EROW] = (short)(u23 >> 16);
            } else {
                // (a) issue pair t+2 loads (using prefetched seg); prefetch seg for t+3
                float2 n_h0, n_v0, n_h1, n_v1;
                int    sg_n = 0;
                if (t < T_IN - 2) {
                    const int n  = 32 * (t + 2) + nloc;
                    const int hb = sg_c;
                    n_h0 = *(const float2*)&hist[((size_t)ts * BHERO + hb) * 2];
                    n_v0 = *(const float2*)&nbrs[((size_t)ts * N_NBR + n0 + n) * 2];
                    n_h1 = *(const float2*)&hist[((size_t)(ts + 8) * BHERO + hb) * 2];
                    n_v1 = *(const float2*)&nbrs[((size_t)(ts + 8) * N_NBR + n0 + n) * 2];
                }
                if (t < T_IN - 3) sg_n = seg[n0 + 32 * (t + 3) + nloc];
                // (b) write pair t+1 from regs loaded last interval (HBM latency hidden)
                if (t < T_IN - 1) {
                    unsigned* dst = (unsigned*)&rela2[(t + 1) & 1][nloc][0];
                    dst[ts]     = pk2(c_h0.x - c_v0.x, c_h0.y - c_v0.y);
                    dst[ts + 8] = pk2(c_h1.x - c_v1.x, c_h1.y - c_v1.y);
                }
                // (c) GEMM pair t (written last interval): wave i covers local tile i>>1, 2 col-tiles
                const int i   = w - 4;
                const int lrt = i >> 1;
                const int ct0 = (i & 1) * 2;
                bf16x8 a = *(const bf16x8*)&rela2[t & 1][lrt * 16 + r][8 * lg];
                #pragma unroll
                for (int cc2 = 0; cc2 < 2; ++cc2) {
                    f32x4 acc = {biasn[cc2], biasn[cc2], biasn[cc2], biasn[cc2]};
                    acc = __builtin_amdgcn_mfma_f32_16x16x32_bf16(a, BfN[cc2], acc, 0, 0, 0);
                    float m4 = fmaxf(fmaxf(acc[0], acc[1]), fmaxf(acc[2], acc[3]));
                    m4 = fmaxf(m4, __shfl_xor(m4, 16));
                    m4 = fmaxf(m4, __shfl_xor(m4, 32));
                    if (l < 16) pmax[2 * t + lrt][(ct0 + cc2) * 16 + r] = m4;
                }
                // (d) rotate pipeline regs
                c_h0 = n_h0; c_v0 = n_v0; c_h1 = n_h1; c_v1 = n_v1;
                sg_c = sg_n;
            }
            bar_lgkm();                             // h(t) + pair-(t+1) rela + pair-t pmax ready
            rbase += SLABE; wbase += SLABE;
        }
    }

    // ---------------- P3: enc_s = [hist_e | scene_d], zero decoder slab 0 ----------------
    #pragma unroll
    for (int it = 0; it < 2; ++it) {
        const int s = tid + 512 * it;               // 1024 tasks: (m, col)
        const int m = s >> 6, col = s & 63;
        const float* wd = Wdyn + (size_t)(col & 31) * ENC;
        float a = bdyn[col & 31];
        if (col < 32) {
            const short* hp = &slab[T_IN][m][32];
            #pragma unroll
            for (int kb = 0; kb < 8; ++kb) {
                bf16x8 hv = *(const bf16x8*)(hp + kb * 8);
                #pragma unroll
                for (int e = 0; e < 8; ++e)
                    a = fmaf(bf2f(hv[e]), wd[kb * 8 + e], a);
            }
        } else {
            #pragma unroll
            for (int kb = 0; kb < 16; ++kb) {
                float4 p0 = *(const float4*)&pmax[2 * m][kb * 4];
                float4 p1 = *(const float4*)&pmax[2 * m + 1][kb * 4];
                a = fmaf(lrelu(fmaxf(p0.x, p1.x)), wd[kb * 4 + 0], a);
                a = fmaf(lrelu(fmaxf(p0.y, p1.y)), wd[kb * 4 + 1], a);
                a = fmaf(lrelu(fmaxf(p0.z, p1.z)), wd[kb * 4 + 2], a);
                a = fmaf(lrelu(fmaxf(p0.w, p1.w)), wd[kb * 4 + 3], a);
            }
        }
        enc_s[m][col] = lrelu(a);
    }
    for (int i = tid; i < 16 * DROW; i += 512) ((short*)hist_s)[i] = 0;   // zero h(0)
    bar_lgkm();                                     // enc_s + decoder slab0 ready

    // ---------------- P4: decoder frags (prescaled) + xw prologue + 25-step LSTM ----------------
    const int u0 = w * 16;
    bf16x8 BfD[4][4];
    float  biasD[4];
    float  sjD[4];
    #pragma unroll
    for (int j = 0; j < 4; ++j) {
        const float sj  = (j == 2) ? (2.f * L2E) : L2E;
        const int   col = j * DEC + u0 + r;
        sjD[j]   = sj;
        biasD[j] = (bihD[col] + bhhD[col]) * sj;
        #pragma unroll
        for (int c = 0; c < 4; ++c) {
            const float* src = WhhD + (size_t)col * DEC + c * 32 + 8 * lg;
            BfD[j][c] = mk_frag_s(*(const float4*)src, *(const float4*)(src + 4), sj);
        }
    }
    f32x4 xwf[4];
    {
        bf16x8 aE[2];
        #pragma unroll
        for (int c = 0; c < 2; ++c) {
            float4 f0 = *(const float4*)&enc_s[r][c * 32 + 8 * lg];
            float4 f1 = *(const float4*)&enc_s[r][c * 32 + 8 * lg + 4];
            aE[c] = mk_frag(f0, f1);
        }
        #pragma unroll
        for (int j = 0; j < 4; ++j) {
            const int col = j * DEC + u0 + r;
            f32x4 a = {biasD[j], biasD[j], biasD[j], biasD[j]};
            #pragma unroll
            for (int c = 0; c < 2; ++c) {
                const float* src = WihD + (size_t)col * (2 * DYN) + c * 32 + 8 * lg;
                a = __builtin_amdgcn_mfma_f32_16x16x32_bf16(
                        aE[c], mk_frag_s(*(const float4*)src, *(const float4*)(src + 4), sjD[j]),
                        a, 0, 0, 0);
            }
            xwf[j] = a;
        }
    }

    f32x4 cst = {0.f, 0.f, 0.f, 0.f};
    {
        const char* rbase = lds_raw + (size_t)r * (DROW * 2);
        char*       wbase = lds_raw + SLABD + (size_t)(4 * lg) * (DROW * 2) + (size_t)(u0 + r) * 2;
        #pragma unroll 1
        for (int t = 0; t < T_OUT; ++t) {
            const short* rp = (const short*)rbase;
            bf16x8 a_[4];
            #pragma unroll
            for (int c = 0; c < 4; ++c)
                a_[c] = *(const bf16x8*)(rp + (4 * c + lg) * 8);
            f32x4 acc[4];
            #pragma unroll
            for (int j = 0; j < 4; ++j) {
                f32x4 aA = xwf[j];
                f32x4 aB = (f32x4){0.f, 0.f, 0.f, 0.f};
                aA = __builtin_amdgcn_mfma_f32_16x16x32_bf16(a_[0], BfD[j][0], aA, 0, 0, 0);
                aB = __builtin_amdgcn_mfma_f32_16x16x32_bf16(a_[1], BfD[j][1], aB, 0, 0, 0);
                aA = __builtin_amdgcn_mfma_f32_16x16x32_bf16(a_[2], BfD[j][2], aA, 0, 0, 0);
                aB = __builtin_amdgcn_mfma_f32_16x16x32_bf16(a_[3], BfD[j][3], aB, 0, 0, 0);
                acc[j] = aA + aB;
            }
            float hq[4];
            #pragma unroll
            for (int q = 0; q < 4; ++q) {
                float ii = sigm2(acc[0][q]);
                float ff = sigm2(acc[1][q]);
                float gg = tanh2(acc[2][q]);
                float oo = sigm2(acc[3][q]);
                float cc = fmaf(ff, cst[q], ii * gg);
                cst[q] = cc;
                hq[q] = oo * tanhc(cc);
            }
            unsigned u01 = pk2(hq[0], hq[1]), u23 = pk2(hq[2], hq[3]);
            short* wp = (short*)wbase;
            wp[0 * DROW] = (short)u01; wp[1 * DROW] = (short)(u01 >> 16);
            wp[2 * DROW] = (short)u23; wp[3 * DROW] = (short)(u23 >> 16);
            bar_lgkm();                             // h(t) ready (slab t+1 was unread)
            rbase += SLABD; wbase += SLABD;
        }
    }

    // ---------------- P5: deferred output head ----------------
    if (tid < T_OUT * 16) {
        const int t = tid >> 4, m = tid & 15;
        const short* hp = &hist_s[t + 1][m][0];
        float o0 = bop_s[0], o1 = bop_s[1];
        #pragma unroll
        for (int ub = 0; ub < DEC / 8; ++ub) {
            bf16x8 hv = *(const bf16x8*)(hp + ub * 8);
            #pragma unroll
            for (int e = 0; e < 8; ++e) {
                float h = bf2f(hv[e]);
                o0 = fmaf(h, wop_s[0][ub * 8 + e], o0);
                o1 = fmaf(h, wop_s[1][ub * 8 + e], o1);
            }
        }
        *(float2*)(fut + ((size_t)t * BHERO + b0 + m) * 2) = make_float2(o0, o1);
    }
}

extern "C" void kernel_launch(void* const* d_in, const int* in_sizes, int n_in,
                              void* d_out, int out_size, void* d_ws, size_t ws_size,
                              hipStream_t stream) {
    (void)d_ws; (void)ws_size; (void)in_sizes; (void)n_in; (void)out_size;
    const float* hist  = (const float*)d_in[0];
    const float* nbrs  = (const float*)d_in[1];
    const float* Wip   = (const float*)d_in[2];
    const float* bip   = (const float*)d_in[3];
    const float* Wih_e = (const float*)d_in[4];
    const float* Whh_e = (const float*)d_in[5];
    const float* bih_e = (const float*)d_in[6];
    const float* bhh_e = (const float*)d_in[7];
    const float* Wdyn  = (const float*)d_in[8];
    const float* bdyn  = (const float*)d_in[9];
    const float* Wnbr  = (const float*)d_in[10];
    const float* bnbr  = (const float*)d_in[11];
    const float* Wih_d = (const float*)d_in[12];
    const float* Whh_d = (const float*)d_in[13];
    const float* bih_d = (const float*)d_in[14];
    const float* bhh_d = (const float*)d_in[15];
    const float* Wop   = (const float*)d_in[16];
    const float* bop   = (const float*)d_in[17];
    const int*   seg   = (const int*)d_in[18];
    float* fut = (float*)d_out;

    hipLaunchKernelGGL(highway_fused, dim3(BHERO / 16), dim3(512), 0, stream,
                       hist, nbrs, Wip, bip, Wih_e, Whh_e, bih_e, bhh_e, Wdyn, bdyn,
                       Wnbr, bnbr, Wih_d, Whh_d, bih_d, bhh_d, Wop, bop, seg, fut);
}